// Round 4
// baseline (582.159 us; speedup 1.0000x reference)
//
#include <hip/hip_runtime.h>
#include <hip/hip_bf16.h>

#define D_DIM 768
#define B_DIM 8192
#define NCHUNK 32   // column chunks (grid.y of main kernel)
#define CT 2        // col-tiles of 128 per chunk
#define BM 128
#define BN 128
#define BK 64
#define CAP 32      // survivor buffer slots per row per tile

typedef __attribute__((ext_vector_type(8))) short short8;
typedef __attribute__((ext_vector_type(4))) float f32x4;
typedef __attribute__((ext_vector_type(4))) unsigned short ushort4v;

// ws layout (bytes)
#define WS_XB   0                               // bf16[8192*768] = 12,582,912
#define WS_SQ   12582912                        // float[8192]
#define WS_THR  12615680                        // float[8192]
#define WS_CAND 12648448                        // float[8192*32*8] = 8,388,608
#define WS_ACC  21037056                        // float acc + int completion counter

__device__ __forceinline__ void gl_lds16(const void* g, void* lds) {
  __builtin_amdgcn_global_load_lds(
      (const __attribute__((address_space(1))) unsigned int*)g,
      (__attribute__((address_space(3))) unsigned int*)lds, 16, 0, 0);
}

// maintain v[0..5] = six smallest seen, sorted ascending (v[5] = max)
__device__ __forceinline__ void ins6(float c, float* v) {
  if (c < v[5]) {
    v[5] = c;
#pragma unroll
    for (int s = 5; s > 0; --s) {
      float lo = fminf(v[s - 1], v[s]);
      float hi = fmaxf(v[s - 1], v[s]);
      v[s - 1] = lo;
      v[s] = hi;
    }
  }
}

// Shared 128x128 Gram tile: staging with XOR swizzle + MFMA K-loop.
// Used by BOTH seed and main kernels -> bit-identical acc values, which makes
// the seed threshold + "<=" collection provably exact.
__device__ __forceinline__ void gram_tile(
    const unsigned short* __restrict__ xb, int rowBase, int colBase,
    char* smem, f32x4 (&acc)[4][4]) {
  unsigned short* As = (unsigned short*)smem;
  unsigned short* Bs = (unsigned short*)(smem + 16384);
  const int t = threadIdx.x;
  const int lane = t & 63;
  const int w = t >> 6;
  const int wm = w >> 1, wn = w & 1;
  const int quad = lane >> 4, m16 = lane & 15;

  const f32x4 zero = {0.0f, 0.0f, 0.0f, 0.0f};
#pragma unroll
  for (int i = 0; i < 4; ++i)
#pragma unroll
    for (int j = 0; j < 4; ++j) acc[i][j] = zero;

  for (int kt = 0; kt < D_DIM / BK; ++kt) {
    const int k0 = kt * BK;
    __syncthreads();
#pragma unroll
    for (int q = 0; q < 4; ++q) {
      const int e = q * 2048 + t * 8;          // bf16 element index in [128][64] tile
      const int r = e >> 6;
      const int seg = (e >> 3) & 7;
      const int srcOff = r * D_DIM + ((seg ^ (r & 7)) * 8);
      gl_lds16(xb + (size_t)rowBase * D_DIM + k0 + srcOff, (char*)As + (size_t)e * 2);
      gl_lds16(xb + (size_t)colBase * D_DIM + k0 + srcOff, (char*)Bs + (size_t)e * 2);
    }
    __syncthreads();
#pragma unroll
    for (int kk = 0; kk < 2; ++kk) {
      short8 a[4], b[4];
#pragma unroll
      for (int i = 0; i < 4; ++i) {
        const int R = wm * 64 + i * 16 + m16;
        const int s = (kk * 4 + quad) ^ (R & 7);
        a[i] = *(const short8*)(As + R * 64 + s * 8);
      }
#pragma unroll
      for (int j = 0; j < 4; ++j) {
        const int R = wn * 64 + j * 16 + m16;
        const int s = (kk * 4 + quad) ^ (R & 7);
        b[j] = *(const short8*)(Bs + R * 64 + s * 8);
      }
#pragma unroll
      for (int i = 0; i < 4; ++i)
#pragma unroll
        for (int j = 0; j < 4; ++j)
          acc[i][j] = __builtin_amdgcn_mfma_f32_16x16x32_bf16(a[i], b[j], acc[i][j], 0, 0, 0);
    }
  }
}

// kernel 1: cast fp32 -> bf16 (vectorized), row sum-of-squares of bf16 values.
__global__ __launch_bounds__(256) void cast_sq_kernel(
    const float* __restrict__ x, unsigned short* __restrict__ xb,
    float* __restrict__ sq, float* __restrict__ accw) {
  const int t = threadIdx.x;
  const int w = t >> 6, lane = t & 63;
  const int row = blockIdx.x * 4 + w;
  if (blockIdx.x == 0 && t == 0) { accw[0] = 0.0f; ((int*)accw)[1] = 0; }
  const f32x4* xr = (const f32x4*)(x + (size_t)row * D_DIM);
  ushort4v* xbr = (ushort4v*)(xb + (size_t)row * D_DIM);
  float s = 0.0f;
#pragma unroll
  for (int c = 0; c < 3; ++c) {
    const int idx = c * 64 + lane;
    f32x4 v = xr[idx];
    ushort4v u;
#pragma unroll
    for (int e = 0; e < 4; ++e) {
      __hip_bfloat16 h = __float2bfloat16(v[e]);
      unsigned short us;
      __builtin_memcpy(&us, &h, 2);
      u[e] = us;
      float vb = __bfloat162float(h);
      s += vb * vb;
    }
    xbr[idx] = u;
  }
#pragma unroll
  for (int off = 32; off > 0; off >>= 1) s += __shfl_down(s, off, 64);
  if (lane == 0) sq[row] = s;
}

// kernel 2: seed thresholds — per row, 6th-smallest D over sample cols [0,128).
__global__ __launch_bounds__(256) void seed_thr_kernel(
    const unsigned short* __restrict__ xb, const float* __restrict__ sq,
    float* __restrict__ thr) {
  __shared__ __align__(16) char smem[40960];
  float* distS = (float*)smem;                 // [64][132], aliases staging
  float* candS = (float*)(smem + 34320);       // [64][24]

  const int t = threadIdx.x;
  const int lane = t & 63;
  const int w = t >> 6;
  const int wm = w >> 1, wn = w & 1;
  const int quad = lane >> 4, m16 = lane & 15;
  const int rowBase = blockIdx.x * BM;

  float rsq[16];
#pragma unroll
  for (int i = 0; i < 4; ++i)
#pragma unroll
    for (int r = 0; r < 4; ++r)
      rsq[i * 4 + r] = sq[rowBase + wm * 64 + i * 16 + quad * 4 + r];
  float csq[4];
#pragma unroll
  for (int j = 0; j < 4; ++j) csq[j] = sq[wn * 64 + j * 16 + m16];  // colBase = 0

  f32x4 acc[4][4];
  gram_tile(xb, rowBase, 0, smem, acc);

  float run[6];
#pragma unroll
  for (int s = 0; s < 6; ++s) run[s] = 1e30f;

  for (int h = 0; h < 2; ++h) {
    __syncthreads();
    if (wm == h) {
      // C layout: col = lane&15, row = quad*4 + reg  [verified m89/m91]
#pragma unroll
      for (int i = 0; i < 4; ++i)
#pragma unroll
        for (int j = 0; j < 4; ++j)
#pragma unroll
          for (int r = 0; r < 4; ++r) {
            const int row_l = i * 16 + quad * 4 + r;
            const int col = wn * 64 + j * 16 + m16;
            // EXACT same expression as main kernel's D
            distS[row_l * 132 + col] =
                fmaf(-2.0f, acc[i][j][r], csq[j]) + rsq[i * 4 + r];
          }
    }
    __syncthreads();
    {
      const int row_l = t >> 2, seg = t & 3;
      const f32x4* dr4 = (const f32x4*)(distS + row_l * 132 + seg * 32);
      float v[6];
#pragma unroll
      for (int s = 0; s < 6; ++s) v[s] = 1e30f;
#pragma unroll
      for (int c4 = 0; c4 < 8; ++c4) {
        f32x4 dv = dr4[c4];
        ins6(dv[0], v); ins6(dv[1], v); ins6(dv[2], v); ins6(dv[3], v);
      }
#pragma unroll
      for (int s = 0; s < 6; ++s) candS[row_l * 24 + seg * 6 + s] = v[s];
    }
    __syncthreads();
    if ((t >> 6) == h) {
      const int row_l = t - h * 64;
#pragma unroll
      for (int c = 0; c < 24; ++c) ins6(candS[row_l * 24 + c], run);
    }
  }
  if (t < BM) thr[rowBase + t] = run[5];
}

// kernel 3: fused Gram tile + threshold-gated top-6 collection (all tiles fast).
__global__ __launch_bounds__(256) void knn_gemm_kernel(
    const unsigned short* __restrict__ xb, const float* __restrict__ sq,
    const float* __restrict__ thr, float* __restrict__ cand) {
  __shared__ __align__(16) char smem[40960];
  float* candbufS = (float*)smem;              // [128][CAP] = 16 KB, aliases staging
  float* distS = (float*)smem;                 // [64][132] (fallback only)
  int* cntS = (int*)(smem + 33792);            // [128]
  int* flagS = (int*)(smem + 34304);           // [1]
  float* candS = (float*)(smem + 34320);       // [64][24] (fallback only)

  const int t = threadIdx.x;
  const int lane = t & 63;
  const int w = t >> 6;
  const int wm = w >> 1, wn = w & 1;
  const int quad = lane >> 4, m16 = lane & 15;
  const int rowBase = blockIdx.x * BM;
  const int chunk = blockIdx.y;

  float rsq[16];
#pragma unroll
  for (int i = 0; i < 4; ++i)
#pragma unroll
    for (int r = 0; r < 4; ++r)
      rsq[i * 4 + r] = sq[rowBase + wm * 64 + i * 16 + quad * 4 + r];

  // per-lane threshold: max over the lane's 4-row group (upper bound on each
  // row's exact thr -> superset collection, still exact after top-6 merge)
  float thrI[4];
#pragma unroll
  for (int i = 0; i < 4; ++i) {
    const int base = rowBase + wm * 64 + i * 16 + quad * 4;
    thrI[i] = fmaxf(fmaxf(thr[base], thr[base + 1]),
                    fmaxf(thr[base + 2], thr[base + 3]));
  }

  float run[6];
#pragma unroll
  for (int s = 0; s < 6; ++s) run[s] = 1e30f;

  for (int ct = 0; ct < CT; ++ct) {
    const int colBase = chunk * (CT * BN) + ct * BN;
    float csq[4];
#pragma unroll
    for (int j = 0; j < 4; ++j)
      csq[j] = sq[colBase + wn * 64 + j * 16 + m16];

    f32x4 acc[4][4];
    gram_tile(xb, rowBase, colBase, smem, acc);

    __syncthreads();  // staging reads done; safe to overwrite aliased bufs
    if (t < BM) cntS[t] = 0;
    if (t == 0) *flagS = 0;
    __syncthreads();
#pragma unroll
    for (int i = 0; i < 4; ++i)
#pragma unroll
      for (int j = 0; j < 4; ++j)
#pragma unroll
        for (int r = 0; r < 4; ++r) {
          const float D = fmaf(-2.0f, acc[i][j][r], csq[j]) + rsq[i * 4 + r];
          if (D <= thrI[i]) {
            const int row = wm * 64 + i * 16 + quad * 4 + r;
            const int slot = atomicAdd(&cntS[row], 1);
            if (slot < CAP) candbufS[row * CAP + slot] = D;
          }
        }
    __syncthreads();
    if (t < BM) {
      const int n = cntS[t];
      if (n <= CAP) {
        for (int c = 0; c < n; ++c) ins6(candbufS[t * CAP + c], run);
      } else {
        *flagS = 1;  // benign same-value race
      }
    }
    __syncthreads();
    if (*flagS) {
      // exact fallback (run probability ~0): full-tile D dump + scan; only
      // overflowed rows' owners merge (others already merged candbuf).
      for (int h = 0; h < 2; ++h) {
        __syncthreads();
        if (wm == h) {
#pragma unroll
          for (int i = 0; i < 4; ++i)
#pragma unroll
            for (int j = 0; j < 4; ++j)
#pragma unroll
              for (int r = 0; r < 4; ++r) {
                const int row_l = i * 16 + quad * 4 + r;
                const int col = wn * 64 + j * 16 + m16;
                distS[row_l * 132 + col] =
                    fmaf(-2.0f, acc[i][j][r], csq[j]) + rsq[i * 4 + r];
              }
        }
        __syncthreads();
        {
          const int row_l = t >> 2, seg = t & 3;
          const f32x4* dr4 = (const f32x4*)(distS + row_l * 132 + seg * 32);
          float v[6];
#pragma unroll
          for (int s = 0; s < 6; ++s) v[s] = 1e30f;
#pragma unroll
          for (int c4 = 0; c4 < 8; ++c4) {
            f32x4 dv = dr4[c4];
            ins6(dv[0], v); ins6(dv[1], v); ins6(dv[2], v); ins6(dv[3], v);
          }
#pragma unroll
          for (int s = 0; s < 6; ++s) candS[row_l * 24 + seg * 6 + s] = v[s];
        }
        __syncthreads();
        if ((t >> 6) == h && cntS[t] > CAP) {
          const int row_l = t - h * 64;
#pragma unroll
          for (int c = 0; c < 24; ++c) ins6(candS[row_l * 24 + c], run);
        }
      }
    }
  }

  if (t < BM) {
    float* o = cand + ((size_t)(rowBase + t) * NCHUNK + chunk) * 8;
#pragma unroll
    for (int s = 0; s < 6; ++s) o[s] = run[s];
  }
}

// kernel 4: per-row merge (d^2) -> sqrt -> log -> sum -> finalize
__global__ __launch_bounds__(256) void knn_merge_kernel(
    const float* __restrict__ cand, float* __restrict__ accw,
    float* __restrict__ out) {
  const int r = blockIdx.x * 256 + threadIdx.x;
  const float* cr = cand + (size_t)r * (NCHUNK * 8);
  float v[6];
#pragma unroll
  for (int s = 0; s < 6; ++s) v[s] = 1e30f;
  for (int c = 0; c < NCHUNK; ++c) {
#pragma unroll
    for (int s = 0; s < 6; ++s) ins6(cr[c * 8 + s], v);
  }
  const float mean = (sqrtf(fmaxf(v[1], 0.0f)) + sqrtf(fmaxf(v[2], 0.0f)) +
                      sqrtf(fmaxf(v[3], 0.0f)) + sqrtf(fmaxf(v[4], 0.0f)) +
                      sqrtf(fmaxf(v[5], 0.0f))) * 0.2f;
  float term = logf(mean + 1e-8f);
#pragma unroll
  for (int off = 32; off > 0; off >>= 1) term += __shfl_down(term, off, 64);
  __shared__ float red[4];
  if ((threadIdx.x & 63) == 0) red[threadIdx.x >> 6] = term;
  __syncthreads();
  if (threadIdx.x == 0) {
    atomicAdd(accw, red[0] + red[1] + red[2] + red[3]);
    __threadfence();
    const int old = atomicAdd((int*)accw + 1, 1);
    if (old == (int)gridDim.x - 1) {
      __threadfence();
      const float tot = atomicAdd(accw, 0.0f);
      out[0] = -tot * (1.0f / 8192.0f);
    }
  }
}

extern "C" void kernel_launch(void* const* d_in, const int* in_sizes, int n_in,
                              void* d_out, int out_size, void* d_ws, size_t ws_size,
                              hipStream_t stream) {
  const float* x = (const float*)d_in[0];
  float* out = (float*)d_out;
  char* ws = (char*)d_ws;
  unsigned short* xb = (unsigned short*)(ws + WS_XB);
  float* sq = (float*)(ws + WS_SQ);
  float* thrb = (float*)(ws + WS_THR);
  float* cand = (float*)(ws + WS_CAND);
  float* accw = (float*)(ws + WS_ACC);

  cast_sq_kernel<<<B_DIM / 4, 256, 0, stream>>>(x, xb, sq, accw);
  seed_thr_kernel<<<B_DIM / BM, 256, 0, stream>>>(xb, sq, thrb);
  knn_gemm_kernel<<<dim3(B_DIM / BM, NCHUNK), 256, 0, stream>>>(xb, sq, thrb, cand);
  knn_merge_kernel<<<B_DIM / 256, 256, 0, stream>>>(cand, accw, out);
}

// Round 5
// 309.077 us; speedup vs baseline: 1.8835x; 1.8835x over previous
//
#include <hip/hip_runtime.h>
#include <hip/hip_bf16.h>

#define D_DIM 768
#define B_DIM 8192
#define NCHUNK 32   // column chunks (grid.y of main kernel)
#define CT 2        // col-tiles of 128 per chunk
#define BM 128
#define BN 128
#define BK 64
#define CAP 32      // survivor slots per row per tile
#define SEED_TILES 2  // seed sample = 256 columns

typedef __attribute__((ext_vector_type(8))) short short8;
typedef __attribute__((ext_vector_type(4))) float f32x4;
typedef __attribute__((ext_vector_type(4))) unsigned short ushort4v;

// ws layout (bytes)
#define WS_XB   0                               // bf16[8192*768] = 12,582,912
#define WS_SQ   12582912                        // float[8192]
#define WS_THR  12615680                        // float[8192]  (s-space gates)
#define WS_CAND 12648448                        // float[8192*32*8] = 8,388,608
#define WS_ACC  21037056                        // float acc + int completion counter

__device__ __forceinline__ void gl_lds16(const void* g, void* lds) {
  __builtin_amdgcn_global_load_lds(
      (const __attribute__((address_space(1))) unsigned int*)g,
      (__attribute__((address_space(3))) unsigned int*)lds, 16, 0, 0);
}

__device__ __forceinline__ float bf2f(unsigned short u) {
  unsigned int x = ((unsigned int)u) << 16;
  float f;
  __builtin_memcpy(&f, &x, 4);
  return f;
}

// maintain v[0..5] = six smallest seen, sorted ascending (v[5] = max)
__device__ __forceinline__ void ins6(float c, float* v) {
  if (c < v[5]) {
    v[5] = c;
#pragma unroll
    for (int s = 5; s > 0; --s) {
      float lo = fminf(v[s - 1], v[s]);
      float hi = fmaxf(v[s - 1], v[s]);
      v[s - 1] = lo;
      v[s] = hi;
    }
  }
}

// Shared 128x128 Gram tile (XOR-swizzled staging + MFMA K-loop). Used by BOTH
// seed and main kernels -> bit-identical acc, making seed-gate + "<=" exact.
__device__ __forceinline__ void gram_tile(
    const unsigned short* __restrict__ xb, int rowBase, int colBase,
    char* smem, f32x4 (&acc)[4][4]) {
  unsigned short* As = (unsigned short*)smem;
  unsigned short* Bs = (unsigned short*)(smem + 16384);
  const int t = threadIdx.x;
  const int lane = t & 63;
  const int w = t >> 6;
  const int wm = w >> 1, wn = w & 1;
  const int quad = lane >> 4, m16 = lane & 15;

  const f32x4 zero = {0.0f, 0.0f, 0.0f, 0.0f};
#pragma unroll
  for (int i = 0; i < 4; ++i)
#pragma unroll
    for (int j = 0; j < 4; ++j) acc[i][j] = zero;

  for (int kt = 0; kt < D_DIM / BK; ++kt) {
    const int k0 = kt * BK;
    __syncthreads();
#pragma unroll
    for (int q = 0; q < 4; ++q) {
      const int e = q * 2048 + t * 8;          // bf16 element index in [128][64] tile
      const int r = e >> 6;
      const int seg = (e >> 3) & 7;
      const int srcOff = r * D_DIM + ((seg ^ (r & 7)) * 8);
      gl_lds16(xb + (size_t)rowBase * D_DIM + k0 + srcOff, (char*)As + (size_t)e * 2);
      gl_lds16(xb + (size_t)colBase * D_DIM + k0 + srcOff, (char*)Bs + (size_t)e * 2);
    }
    __syncthreads();
#pragma unroll
    for (int kk = 0; kk < 2; ++kk) {
      short8 a[4], b[4];
#pragma unroll
      for (int i = 0; i < 4; ++i) {
        const int R = wm * 64 + i * 16 + m16;
        const int s = (kk * 4 + quad) ^ (R & 7);
        a[i] = *(const short8*)(As + R * 64 + s * 8);
      }
#pragma unroll
      for (int j = 0; j < 4; ++j) {
        const int R = wn * 64 + j * 16 + m16;
        const int s = (kk * 4 + quad) ^ (R & 7);
        b[j] = *(const short8*)(Bs + R * 64 + s * 8);
      }
#pragma unroll
      for (int i = 0; i < 4; ++i)
#pragma unroll
        for (int j = 0; j < 4; ++j)
          acc[i][j] = __builtin_amdgcn_mfma_f32_16x16x32_bf16(a[i], b[j], acc[i][j], 0, 0, 0);
    }
  }
}

// kernel 1: cast fp32 -> bf16 (vectorized), row sum-of-squares of bf16 values.
__global__ __launch_bounds__(256) void cast_sq_kernel(
    const float* __restrict__ x, unsigned short* __restrict__ xb,
    float* __restrict__ sq, float* __restrict__ accw) {
  const int t = threadIdx.x;
  const int w = t >> 6, lane = t & 63;
  const int row = blockIdx.x * 4 + w;
  if (blockIdx.x == 0 && t == 0) { accw[0] = 0.0f; ((int*)accw)[1] = 0; }
  const f32x4* xr = (const f32x4*)(x + (size_t)row * D_DIM);
  ushort4v* xbr = (ushort4v*)(xb + (size_t)row * D_DIM);
  float s = 0.0f;
#pragma unroll
  for (int c = 0; c < 3; ++c) {
    const int idx = c * 64 + lane;
    f32x4 v = xr[idx];
    ushort4v u;
#pragma unroll
    for (int e = 0; e < 4; ++e) {
      __hip_bfloat16 h = __float2bfloat16(v[e]);
      unsigned short us;
      __builtin_memcpy(&us, &h, 2);
      u[e] = us;
      float vb = __bfloat162float(h);
      s += vb * vb;
    }
    xbr[idx] = u;
  }
#pragma unroll
  for (int off = 32; off > 0; off >>= 1) s += __shfl_down(s, off, 64);
  if (lane == 0) sq[row] = s;
}

// kernel 2: seed gates — per row, 6th-smallest s over cols [0, 256).
// s(r,c) = csq_c - 2*dot(r,c); d^2 = s + rsq_r is monotone in s per row, so
// the 6th-smallest s corresponds to the 6th-smallest distance.
__global__ __launch_bounds__(256) void seed_thr_kernel(
    const unsigned short* __restrict__ xb, const float* __restrict__ sq,
    float* __restrict__ sthr) {
  __shared__ __align__(16) char smem[39936];
  float* distS = (float*)smem;                 // [64][132], aliases staging
  float* candS = (float*)(smem + 33792);       // [64][24]

  const int t = threadIdx.x;
  const int lane = t & 63;
  const int w = t >> 6;
  const int wm = w >> 1, wn = w & 1;
  const int quad = lane >> 4, m16 = lane & 15;
  const int rowBase = blockIdx.x * BM;

  float run[6];
#pragma unroll
  for (int s = 0; s < 6; ++s) run[s] = 1e30f;

  for (int ct = 0; ct < SEED_TILES; ++ct) {
    const int colBase = ct * BN;
    float csq[4];
#pragma unroll
    for (int j = 0; j < 4; ++j) csq[j] = sq[colBase + wn * 64 + j * 16 + m16];

    f32x4 acc[4][4];
    gram_tile(xb, rowBase, colBase, smem, acc);

    for (int h = 0; h < 2; ++h) {
      __syncthreads();
      if (wm == h) {
        // C layout: col = lane&15, row = quad*4 + reg  [verified m89/m91]
#pragma unroll
        for (int i = 0; i < 4; ++i)
#pragma unroll
          for (int j = 0; j < 4; ++j)
#pragma unroll
            for (int r = 0; r < 4; ++r) {
              const int row_l = i * 16 + quad * 4 + r;
              const int col = wn * 64 + j * 16 + m16;
              // EXACT same expression as main kernel's s
              distS[row_l * 132 + col] = fmaf(-2.0f, acc[i][j][r], csq[j]);
            }
      }
      __syncthreads();
      {
        const int row_l = t >> 2, seg = t & 3;
        const f32x4* dr4 = (const f32x4*)(distS + row_l * 132 + seg * 32);
        float v[6];
#pragma unroll
        for (int s = 0; s < 6; ++s) v[s] = 1e30f;
#pragma unroll
        for (int c4 = 0; c4 < 8; ++c4) {
          f32x4 dv = dr4[c4];
          ins6(dv[0], v); ins6(dv[1], v); ins6(dv[2], v); ins6(dv[3], v);
        }
#pragma unroll
        for (int s = 0; s < 6; ++s) candS[row_l * 24 + seg * 6 + s] = v[s];
      }
      __syncthreads();
      if ((t >> 6) == h) {
        const int row_l = t - h * 64;
#pragma unroll
        for (int c = 0; c < 24; ++c) ins6(candS[row_l * 24 + c], run);
      }
    }
  }
  if (t < BM) sthr[rowBase + t] = run[5];
}

// kernel 3: fused Gram tile + s-space threshold-gated survivor collection.
// No in-kernel fallback: overflow (P ~ 1e-10/row-tile) sets a flag in the
// cand slot; merge kernel recomputes that (row, chunk) exactly.
__global__ __launch_bounds__(256) void knn_gemm_kernel(
    const unsigned short* __restrict__ xb, const float* __restrict__ sq,
    const float* __restrict__ sthr, float* __restrict__ cand) {
  __shared__ __align__(16) char smem[33280];
  float* candbufS = (float*)smem;              // [128][CAP] = 16 KB, aliases staging
  int* cntS = (int*)(smem + 32768);            // [128]

  const int t = threadIdx.x;
  const int lane = t & 63;
  const int w = t >> 6;
  const int wm = w >> 1, wn = w & 1;
  const int quad = lane >> 4, m16 = lane & 15;
  const int rowBase = blockIdx.x * BM;
  const int chunk = blockIdx.y;

  // per-lane gate: max of the lane's 4-row group in s-space (row-offset-free)
  float gate4[4];
#pragma unroll
  for (int i = 0; i < 4; ++i) {
    const int base = rowBase + wm * 64 + i * 16 + quad * 4;
    gate4[i] = fmaxf(fmaxf(sthr[base], sthr[base + 1]),
                     fmaxf(sthr[base + 2], sthr[base + 3]));
  }

  float run[6];
#pragma unroll
  for (int s = 0; s < 6; ++s) run[s] = 1e30f;
  bool ovf = false;  // meaningful for owners (t < 128)

  for (int ct = 0; ct < CT; ++ct) {
    const int colBase = chunk * (CT * BN) + ct * BN;
    float csq[4];
#pragma unroll
    for (int j = 0; j < 4; ++j)
      csq[j] = sq[colBase + wn * 64 + j * 16 + m16];

    f32x4 acc[4][4];
    gram_tile(xb, rowBase, colBase, smem, acc);

    __syncthreads();  // staging reads done; safe to overwrite aliased candbuf
    if (t < BM) cntS[t] = 0;
    __syncthreads();
#pragma unroll
    for (int i = 0; i < 4; ++i)
#pragma unroll
      for (int j = 0; j < 4; ++j)
#pragma unroll
        for (int r = 0; r < 4; ++r) {
          const float s = fmaf(-2.0f, acc[i][j][r], csq[j]);
          if (s <= gate4[i]) {
            const int row = wm * 64 + i * 16 + quad * 4 + r;
            const int slot = atomicAdd(&cntS[row], 1);
            if (slot < CAP) candbufS[row * CAP + slot] = s;
          }
        }
    __syncthreads();
    if (t < BM) {
      const int n = cntS[t];
      const int m = n < CAP ? n : CAP;
      for (int c = 0; c < m; ++c) ins6(candbufS[t * CAP + c], run);
      ovf |= (n > CAP);
    }
    // next gram_tile's first __syncthreads orders candbuf reads vs re-staging
  }

  if (t < BM) {
    float* o = cand + ((size_t)(rowBase + t) * NCHUNK + chunk) * 8;
#pragma unroll
    for (int s = 0; s < 6; ++s) o[s] = run[s];
    o[6] = ovf ? 1.0f : 0.0f;
  }
}

// kernel 4: per-row merge (s-space) -> d^2 -> sqrt -> log -> sum -> finalize.
// Handles the (never-in-practice) overflow flag by exact recompute.
__global__ __launch_bounds__(256) void knn_merge_kernel(
    const float* __restrict__ cand, const float* __restrict__ sq,
    const unsigned short* __restrict__ xb, float* __restrict__ accw,
    float* __restrict__ out) {
  const int r = blockIdx.x * 256 + threadIdx.x;
  const float* cr = cand + (size_t)r * (NCHUNK * 8);
  float v[6];
#pragma unroll
  for (int s = 0; s < 6; ++s) v[s] = 1e30f;
  for (int c = 0; c < NCHUNK; ++c) {
    if (cr[c * 8 + 6] != 0.0f) {
      // exact fallback: recompute row r vs this chunk's 256 cols directly
      const unsigned short* xr = xb + (size_t)r * D_DIM;
      for (int cc = 0; cc < CT * BN; ++cc) {
        const int col = c * (CT * BN) + cc;
        const unsigned short* xc = xb + (size_t)col * D_DIM;
        float dot = 0.0f;
        for (int k = 0; k < D_DIM; ++k) dot = fmaf(bf2f(xr[k]), bf2f(xc[k]), dot);
        ins6(fmaf(-2.0f, dot, sq[col]), v);
      }
    } else {
#pragma unroll
      for (int s = 0; s < 6; ++s) ins6(cr[c * 8 + s], v);
    }
  }
  // v sorted ascending in s-space; self = minimum (d=0) -> drop v[0]
  const float rsq = sq[r];
  const float mean = (sqrtf(fmaxf(v[1] + rsq, 0.0f)) + sqrtf(fmaxf(v[2] + rsq, 0.0f)) +
                      sqrtf(fmaxf(v[3] + rsq, 0.0f)) + sqrtf(fmaxf(v[4] + rsq, 0.0f)) +
                      sqrtf(fmaxf(v[5] + rsq, 0.0f))) * 0.2f;
  float term = logf(mean + 1e-8f);
#pragma unroll
  for (int off = 32; off > 0; off >>= 1) term += __shfl_down(term, off, 64);
  __shared__ float red[4];
  if ((threadIdx.x & 63) == 0) red[threadIdx.x >> 6] = term;
  __syncthreads();
  if (threadIdx.x == 0) {
    atomicAdd(accw, red[0] + red[1] + red[2] + red[3]);
    __threadfence();
    const int old = atomicAdd((int*)accw + 1, 1);
    if (old == (int)gridDim.x - 1) {
      __threadfence();
      const float tot = atomicAdd(accw, 0.0f);
      out[0] = -tot * (1.0f / 8192.0f);
    }
  }
}

extern "C" void kernel_launch(void* const* d_in, const int* in_sizes, int n_in,
                              void* d_out, int out_size, void* d_ws, size_t ws_size,
                              hipStream_t stream) {
  const float* x = (const float*)d_in[0];
  float* out = (float*)d_out;
  char* ws = (char*)d_ws;
  unsigned short* xb = (unsigned short*)(ws + WS_XB);
  float* sq = (float*)(ws + WS_SQ);
  float* sthr = (float*)(ws + WS_THR);
  float* cand = (float*)(ws + WS_CAND);
  float* accw = (float*)(ws + WS_ACC);

  cast_sq_kernel<<<B_DIM / 4, 256, 0, stream>>>(x, xb, sq, accw);
  seed_thr_kernel<<<B_DIM / BM, 256, 0, stream>>>(xb, sq, sthr);
  knn_gemm_kernel<<<dim3(B_DIM / BM, NCHUNK), 256, 0, stream>>>(xb, sq, sthr, cand);
  knn_merge_kernel<<<B_DIM / 256, 256, 0, stream>>>(cand, sq, xb, accw, out);
}

// Round 6
// 286.887 us; speedup vs baseline: 2.0292x; 1.0773x over previous
//
#include <hip/hip_runtime.h>
#include <hip/hip_bf16.h>

#define D_DIM 768
#define B_DIM 8192
#define NTILE 64      // 8192/128 row tiles
#define NPAIR 2080    // NTILE*(NTILE+1)/2 symmetric tile pairs
#define SEED_PARTS 4  // seed sample = 4 x 128 cols
#define BM 128
#define BN 128
#define BK 64
#define CAP 32        // survivor slots per query per tile

typedef __attribute__((ext_vector_type(8))) short short8;
typedef __attribute__((ext_vector_type(4))) float f32x4;
typedef __attribute__((ext_vector_type(4))) unsigned short ushort4v;

// ws layout (bytes)
#define WS_XB   0                            // bf16[8192*768] = 12,582,912
#define WS_SQ   12582912                     // float[8192]
#define WS_GATE 12615680                     // uint[8192] encoded s-gates
#define WS_CAND 12648448                     // float[64 slots][8192 rows][8] = 16,777,216
#define WS_ACC  29425664                     // float acc + int completion counter

__device__ __forceinline__ void gl_lds16(const void* g, void* lds) {
  __builtin_amdgcn_global_load_lds(
      (const __attribute__((address_space(1))) unsigned int*)g,
      (__attribute__((address_space(3))) unsigned int*)lds, 16, 0, 0);
}

__device__ __forceinline__ float bf2f(unsigned short u) {
  unsigned int x = ((unsigned int)u) << 16;
  float f;
  __builtin_memcpy(&f, &x, 4);
  return f;
}

// order-preserving float<->uint encoding (unsigned compare == float compare)
__device__ __forceinline__ unsigned int encf(float f) {
  unsigned int u;
  __builtin_memcpy(&u, &f, 4);
  return (u & 0x80000000u) ? ~u : (u | 0x80000000u);
}
__device__ __forceinline__ float decf(unsigned int k) {
  unsigned int u = (k & 0x80000000u) ? (k ^ 0x80000000u) : ~k;
  float f;
  __builtin_memcpy(&f, &u, 4);
  return f;
}

// maintain v[0..5] = six smallest seen, sorted ascending (v[5] = max)
__device__ __forceinline__ void ins6(float c, float* v) {
  if (c < v[5]) {
    v[5] = c;
#pragma unroll
    for (int s = 5; s > 0; --s) {
      float lo = fminf(v[s - 1], v[s]);
      float hi = fmaxf(v[s - 1], v[s]);
      v[s - 1] = lo;
      v[s] = hi;
    }
  }
}

// Shared 128x128 Gram tile (XOR-swizzled staging + MFMA K-loop). Identical
// dataflow for seed and pair kernels -> bit-identical dots (operand swap
// commutes bitwise per-product and the k-reduction order is fixed).
__device__ __forceinline__ void gram_tile(
    const unsigned short* __restrict__ xb, int rowBase, int colBase,
    char* smem, f32x4 (&acc)[4][4]) {
  unsigned short* As = (unsigned short*)smem;
  unsigned short* Bs = (unsigned short*)(smem + 16384);
  const int t = threadIdx.x;
  const int lane = t & 63;
  const int w = t >> 6;
  const int wm = w >> 1, wn = w & 1;
  const int quad = lane >> 4, m16 = lane & 15;

  const f32x4 zero = {0.0f, 0.0f, 0.0f, 0.0f};
#pragma unroll
  for (int i = 0; i < 4; ++i)
#pragma unroll
    for (int j = 0; j < 4; ++j) acc[i][j] = zero;

  for (int kt = 0; kt < D_DIM / BK; ++kt) {
    const int k0 = kt * BK;
    __syncthreads();
#pragma unroll
    for (int q = 0; q < 4; ++q) {
      const int e = q * 2048 + t * 8;          // bf16 element index in [128][64] tile
      const int r = e >> 6;
      const int seg = (e >> 3) & 7;
      const int srcOff = r * D_DIM + ((seg ^ (r & 7)) * 8);
      gl_lds16(xb + (size_t)rowBase * D_DIM + k0 + srcOff, (char*)As + (size_t)e * 2);
      gl_lds16(xb + (size_t)colBase * D_DIM + k0 + srcOff, (char*)Bs + (size_t)e * 2);
    }
    __syncthreads();
#pragma unroll
    for (int kk = 0; kk < 2; ++kk) {
      short8 a[4], b[4];
#pragma unroll
      for (int i = 0; i < 4; ++i) {
        const int R = wm * 64 + i * 16 + m16;
        const int s = (kk * 4 + quad) ^ (R & 7);
        a[i] = *(const short8*)(As + R * 64 + s * 8);
      }
#pragma unroll
      for (int j = 0; j < 4; ++j) {
        const int R = wn * 64 + j * 16 + m16;
        const int s = (kk * 4 + quad) ^ (R & 7);
        b[j] = *(const short8*)(Bs + R * 64 + s * 8);
      }
#pragma unroll
      for (int i = 0; i < 4; ++i)
#pragma unroll
        for (int j = 0; j < 4; ++j)
          acc[i][j] = __builtin_amdgcn_mfma_f32_16x16x32_bf16(a[i], b[j], acc[i][j], 0, 0, 0);
    }
  }
}

// kernel 1: cast fp32 -> bf16, row sum-of-squares, init gates/acc
__global__ __launch_bounds__(256) void cast_sq_kernel(
    const float* __restrict__ x, unsigned short* __restrict__ xb,
    float* __restrict__ sq, unsigned int* __restrict__ gate,
    float* __restrict__ accw) {
  const int t = threadIdx.x;
  const int w = t >> 6, lane = t & 63;
  const int row = blockIdx.x * 4 + w;
  if (blockIdx.x == 0 && t == 0) { accw[0] = 0.0f; ((int*)accw)[1] = 0; }
  const f32x4* xr = (const f32x4*)(x + (size_t)row * D_DIM);
  ushort4v* xbr = (ushort4v*)(xb + (size_t)row * D_DIM);
  float s = 0.0f;
#pragma unroll
  for (int c = 0; c < 3; ++c) {
    const int idx = c * 64 + lane;
    f32x4 v = xr[idx];
    ushort4v u;
#pragma unroll
    for (int e = 0; e < 4; ++e) {
      __hip_bfloat16 h = __float2bfloat16(v[e]);
      unsigned short us;
      __builtin_memcpy(&us, &h, 2);
      u[e] = us;
      float vb = __bfloat162float(h);
      s += vb * vb;
    }
    xbr[idx] = u;
  }
#pragma unroll
  for (int off = 32; off > 0; off >>= 1) s += __shfl_down(s, off, 64);
  if (lane == 0) { sq[row] = s; gate[row] = 0xFFFFFFFFu; }
}

// kernel 2: seed gates — per (rowtile, part): 6th-smallest s over the part's
// 128 cols; gate[row] = min over parts via atomicMin on encoded floats.
// Any subset's 6th >= global 6th -> "<=" collection is an exact superset.
__global__ __launch_bounds__(256) void seed_thr_kernel(
    const unsigned short* __restrict__ xb, const float* __restrict__ sq,
    unsigned int* __restrict__ gate) {
  __shared__ __align__(16) char smem[39936];
  float* distS = (float*)smem;                 // [64][132], aliases staging
  float* candS = (float*)(smem + 33792);       // [64][24]

  const int t = threadIdx.x;
  const int lane = t & 63;
  const int w = t >> 6;
  const int wm = w >> 1, wn = w & 1;
  const int quad = lane >> 4, m16 = lane & 15;
  const int rowBase = blockIdx.x * BM;
  const int colBase = blockIdx.y * BN;

  f32x4 acc[4][4];
  gram_tile(xb, rowBase, colBase, smem, acc);

  float csq[4];
#pragma unroll
  for (int j = 0; j < 4; ++j) csq[j] = sq[colBase + wn * 64 + j * 16 + m16];

  float run[6];
#pragma unroll
  for (int s = 0; s < 6; ++s) run[s] = 1e30f;

  for (int h = 0; h < 2; ++h) {
    __syncthreads();
    if (wm == h) {
      // C layout: col = lane&15, row = quad*4 + reg  [verified m89/m91]
#pragma unroll
      for (int i = 0; i < 4; ++i)
#pragma unroll
        for (int j = 0; j < 4; ++j)
#pragma unroll
          for (int r = 0; r < 4; ++r) {
            const int row_l = i * 16 + quad * 4 + r;
            const int col = wn * 64 + j * 16 + m16;
            // EXACT same expression as pair kernel's s
            distS[row_l * 132 + col] = fmaf(-2.0f, acc[i][j][r], csq[j]);
          }
    }
    __syncthreads();
    {
      const int row_l = t >> 2, seg = t & 3;
      const f32x4* dr4 = (const f32x4*)(distS + row_l * 132 + seg * 32);
      float v[6];
#pragma unroll
      for (int s = 0; s < 6; ++s) v[s] = 1e30f;
#pragma unroll
      for (int c4 = 0; c4 < 8; ++c4) {
        f32x4 dv = dr4[c4];
        ins6(dv[0], v); ins6(dv[1], v); ins6(dv[2], v); ins6(dv[3], v);
      }
#pragma unroll
      for (int s = 0; s < 6; ++s) candS[row_l * 24 + seg * 6 + s] = v[s];
    }
    __syncthreads();
    if ((t >> 6) == h) {
      const int row_l = t - h * 64;
#pragma unroll
      for (int c = 0; c < 24; ++c) ins6(candS[row_l * 24 + c], run);
    }
  }
  if (t < BM) atomicMin(&gate[rowBase + t], encf(run[5]));
}

// kernel 3: symmetric pair kernel. One 128x128 Gram tile per block serves
// row-queries of tile a (keys = rows of b) AND row-queries of tile b
// (keys = rows of a) from the same dots. Diagonal: row-side only.
__global__ __launch_bounds__(256) void knn_pair_kernel(
    const unsigned short* __restrict__ xb, const float* __restrict__ sq,
    const unsigned int* __restrict__ gate, float* __restrict__ cand) {
  __shared__ __align__(16) char smem[33792];
  float* candbufS = (float*)smem;              // [256][CAP] = 32 KB, aliases staging
  int* cntS = (int*)(smem + 32768);            // [256]

  const int t = threadIdx.x;
  const int lane = t & 63;
  const int w = t >> 6;
  const int wm = w >> 1, wn = w & 1;
  const int quad = lane >> 4, m16 = lane & 15;

  // linear pair index -> (a, b), a <= b
  int a = 0, b;
  {
    int rem = blockIdx.x, span = NTILE;
    while (rem >= span) { rem -= span; ++a; --span; }
    b = a + rem;
  }
  const int rowBase = a * BM, colBase = b * BN;
  const bool diag = (a == b);

  f32x4 acc[4][4];
  gram_tile(xb, rowBase, colBase, smem, acc);

  // loads placed after K-loop to keep its register peak low
  float csq[4], gateB[4];
#pragma unroll
  for (int j = 0; j < 4; ++j) {
    const int c = colBase + wn * 64 + j * 16 + m16;
    csq[j] = sq[c];
    gateB[j] = decf(gate[c]);
  }
  float rsqk[16], gateA4[4];
#pragma unroll
  for (int i = 0; i < 4; ++i) {
    const int base = rowBase + wm * 64 + i * 16 + quad * 4;
    float g = -1e30f;
#pragma unroll
    for (int r = 0; r < 4; ++r) {
      rsqk[i * 4 + r] = sq[base + r];
      g = fmaxf(g, decf(gate[base + r]));
    }
    gateA4[i] = g;
  }

  __syncthreads();  // staging reads done; safe to overwrite aliased candbuf
  cntS[t] = 0;
  __syncthreads();

  // row-side: queries = rows of a, keys = cols (rows of b)
#pragma unroll
  for (int i = 0; i < 4; ++i)
#pragma unroll
    for (int j = 0; j < 4; ++j)
#pragma unroll
      for (int r = 0; r < 4; ++r) {
        const float s = fmaf(-2.0f, acc[i][j][r], csq[j]);
        if (s <= gateA4[i]) {
          const int q = wm * 64 + i * 16 + quad * 4 + r;
          const int slot = atomicAdd(&cntS[q], 1);
          if (slot < CAP) candbufS[q * CAP + slot] = s;
        }
      }
  // col-side: queries = rows of b, keys = rows of a (skip on diagonal: dupes)
  if (!diag) {
#pragma unroll
    for (int i = 0; i < 4; ++i)
#pragma unroll
      for (int j = 0; j < 4; ++j)
#pragma unroll
        for (int r = 0; r < 4; ++r) {
          const float s2 = fmaf(-2.0f, acc[i][j][r], rsqk[i * 4 + r]);
          if (s2 <= gateB[j]) {
            const int q = 128 + wn * 64 + j * 16 + m16;
            const int slot = atomicAdd(&cntS[q], 1);
            if (slot < CAP) candbufS[q * CAP + slot] = s2;
          }
        }
  }
  __syncthreads();

  const int nq = diag ? 128 : 256;
  if (t < nq) {
    float v[6];
#pragma unroll
    for (int s = 0; s < 6; ++s) v[s] = 1e30f;
    const int n = cntS[t];
    const int m = n < CAP ? n : CAP;
    for (int c = 0; c < m; ++c) ins6(candbufS[t * CAP + c], v);
    const int qrow = (t < 128) ? (rowBase + t) : (colBase + (t - 128));
    const int slot = (t < 128) ? b : a;
    float* o = cand + ((size_t)slot * B_DIM + qrow) * 8;
#pragma unroll
    for (int s = 0; s < 6; ++s) o[s] = v[s];
    o[6] = (n > CAP) ? 1.0f : 0.0f;
  }
}

// kernel 4: per-row merge of 64 slots (s-space) -> d -> log -> sum -> finalize
__global__ __launch_bounds__(256) void knn_merge_kernel(
    const float* __restrict__ cand, const float* __restrict__ sq,
    const unsigned short* __restrict__ xb, float* __restrict__ accw,
    float* __restrict__ out) {
  const int r = blockIdx.x * 256 + threadIdx.x;
  float v[6];
#pragma unroll
  for (int s = 0; s < 6; ++s) v[s] = 1e30f;
  for (int c = 0; c < NTILE; ++c) {
    const float* cr = cand + ((size_t)c * B_DIM + r) * 8;
    if (cr[6] != 0.0f) {
      // exact fallback (P ~ 1e-10): recompute row r vs this tile's 128 keys
      const unsigned short* xr = xb + (size_t)r * D_DIM;
      for (int cc = 0; cc < BN; ++cc) {
        const int col = c * BN + cc;
        const unsigned short* xc = xb + (size_t)col * D_DIM;
        float dot = 0.0f;
        for (int k = 0; k < D_DIM; ++k) dot = fmaf(bf2f(xr[k]), bf2f(xc[k]), dot);
        ins6(fmaf(-2.0f, dot, sq[col]), v);
      }
    } else {
#pragma unroll
      for (int s = 0; s < 6; ++s) ins6(cr[s], v);
    }
  }
  // v ascending in s-space; self = minimum (d ~ 0) -> drop v[0]
  const float rsq = sq[r];
  const float mean = (sqrtf(fmaxf(v[1] + rsq, 0.0f)) + sqrtf(fmaxf(v[2] + rsq, 0.0f)) +
                      sqrtf(fmaxf(v[3] + rsq, 0.0f)) + sqrtf(fmaxf(v[4] + rsq, 0.0f)) +
                      sqrtf(fmaxf(v[5] + rsq, 0.0f))) * 0.2f;
  float term = logf(mean + 1e-8f);
#pragma unroll
  for (int off = 32; off > 0; off >>= 1) term += __shfl_down(term, off, 64);
  __shared__ float red[4];
  if ((threadIdx.x & 63) == 0) red[threadIdx.x >> 6] = term;
  __syncthreads();
  if (threadIdx.x == 0) {
    atomicAdd(accw, red[0] + red[1] + red[2] + red[3]);
    __threadfence();
    const int old = atomicAdd((int*)accw + 1, 1);
    if (old == (int)gridDim.x - 1) {
      __threadfence();
      const float tot = atomicAdd(accw, 0.0f);
      out[0] = -tot * (1.0f / 8192.0f);
    }
  }
}

extern "C" void kernel_launch(void* const* d_in, const int* in_sizes, int n_in,
                              void* d_out, int out_size, void* d_ws, size_t ws_size,
                              hipStream_t stream) {
  const float* x = (const float*)d_in[0];
  float* out = (float*)d_out;
  char* ws = (char*)d_ws;
  unsigned short* xb = (unsigned short*)(ws + WS_XB);
  float* sq = (float*)(ws + WS_SQ);
  unsigned int* gate = (unsigned int*)(ws + WS_GATE);
  float* cand = (float*)(ws + WS_CAND);
  float* accw = (float*)(ws + WS_ACC);

  cast_sq_kernel<<<B_DIM / 4, 256, 0, stream>>>(x, xb, sq, gate, accw);
  seed_thr_kernel<<<dim3(B_DIM / BM, SEED_PARTS), 256, 0, stream>>>(xb, sq, gate);
  knn_pair_kernel<<<NPAIR, 256, 0, stream>>>(xb, sq, gate, cand);
  knn_merge_kernel<<<B_DIM / 256, 256, 0, stream>>>(cand, sq, xb, accw, out);
}